// Round 1
// baseline (60.452 us; speedup 1.0000x reference)
//
#include <hip/hip_runtime.h>
#include <math.h>

#define HD 256  // hidden dim D

typedef unsigned int uint32;
typedef __attribute__((ext_vector_type(8))) short bf16x8;   // MFMA A/B frag (4 VGPR)
typedef __attribute__((ext_vector_type(4))) float f32x4;    // MFMA C/D frag

// round-to-nearest-even f32 -> bf16 (finite inputs)
__device__ inline unsigned short f2bf(float f) {
  uint32 u = __float_as_uint(f);
  return (unsigned short)((u + 0x7fffu + ((u >> 16) & 1u)) >> 16);
}
__device__ inline float bflo(uint32 v) { return __uint_as_float(v << 16); }
__device__ inline float bfhi(uint32 v) { return __uint_as_float(v & 0xffff0000u); }

// ---------------------------------------------------------------------------
// Kernel 1 (prep): blocks [0, nbb): segment bounds for both sorted arrays +
// f32->bf16 convert of proj_W.  Blocks [nbb, ...): per-protein weight
// e[p] = exp(ph[p].attn_w)  (logits ~N(0,1) -> unshifted exp safe; group
// softmax is shift-invariant) and the premultiplied bf16 table stored
// CHUNK-MAJOR:  wph[chunk][p][64] , chunk = dim/64.  Each 64-dim slice is
// 20000*128B = 2.56 MB -> fits a 4 MiB per-XCD L2 (the key to kernel 3).
// ---------------------------------------------------------------------------
__global__ __launch_bounds__(256) void prep_kernel(
    const int* __restrict__ mseg, int T, int G, int* __restrict__ gstart,
    const int* __restrict__ g2d, int ND, int* __restrict__ dstart,
    const float* __restrict__ W, int NW, unsigned short* __restrict__ Wbf,
    const float* __restrict__ protein_h, const float* __restrict__ attn_w,
    int np, float* __restrict__ etbl, unsigned short* __restrict__ wph,
    int nbb) {
  int b = blockIdx.x;
  if (b < nbb) {
    int t = b * 256 + threadIdx.x;
    if (t <= T) {
      int cur  = (t < T) ? mseg[t] : G;
      int prev = (t == 0) ? -1 : mseg[t - 1];
      for (int g = prev + 1; g <= cur; ++g) gstart[g] = t;
    }
    if (t <= G) {
      int cur  = (t < G) ? g2d[t] : ND;
      int prev = (t == 0) ? -1 : g2d[t - 1];
      for (int d = prev + 1; d <= cur; ++d) dstart[d] = t;
    }
    if (t < NW) Wbf[t] = f2bf(W[t]);
    return;
  }
  int wave = threadIdx.x >> 6, lane = threadIdx.x & 63;
  int p = (b - nbb) * 4 + wave;
  if (p >= np) return;
  float4 w = ((const float4*)attn_w)[lane];
  float4 v = ((const float4*)(protein_h + (size_t)p * HD))[lane];
  float s = v.x * w.x + v.y * w.y + v.z * w.z + v.w * w.w;
#pragma unroll
  for (int o = 32; o > 0; o >>= 1) s += __shfl_xor(s, o, 64);
  float e = __expf(s);
  if (lane == 0) etbl[p] = e;
  ushort4 st;
  st.x = f2bf(e * v.x); st.y = f2bf(e * v.y);
  st.z = f2bf(e * v.z); st.w = f2bf(e * v.w);
  // lane covers dims lane*4..lane*4+3 -> chunk = lane>>4, within = (lane&15)*4
  *(ushort4*)(wph + ((size_t)(lane >> 4) * np + p) * 64 + (lane & 15) * 4) = st;
}

// ---------------------------------------------------------------------------
// Kernel 2 (coef): one 16-lane quarter per group.  denom_g = sum etbl[row]
// over the group's (contiguous) member range; write per-member packed
// cw[t] = {row, 1/denom_g}.  Turns the downstream pool into a FLAT weighted
// sum with zero per-group reduction work (wph is already premultiplied by e).
// ---------------------------------------------------------------------------
__global__ __launch_bounds__(256) void coef_kernel(
    const int* __restrict__ midx, const float* __restrict__ etbl,
    const int* __restrict__ gstart, int G, uint2* __restrict__ cw) {
  int q = blockIdx.x * 16 + (threadIdx.x >> 4);  // group id
  int ql = threadIdx.x & 15;
  if (q >= G) return;
  int beg = gstart[q], end = gstart[q + 1];
  if (beg >= end) return;
  float d = 0.f;
  for (int c = beg + ql; c < end; c += 16) d += etbl[midx[c]];
  d += __shfl_xor(d, 1, 64); d += __shfl_xor(d, 2, 64);
  d += __shfl_xor(d, 4, 64); d += __shfl_xor(d, 8, 64);
  float inv = 1.f / d;
  for (int c = beg + ql; c < end; c += 16) {
    cw[c] = make_uint2((uint32)midx[c], __float_as_uint(inv));
  }
}

// ---------------------------------------------------------------------------
// Kernel 3 (fused pool + drug-mean, chunked XCD-pinned): one wave per block,
// 2 drugs per block, ONE 64-dim chunk per block.  chunk = (blockIdx%8)>>1:
// blocks round-robin across XCDs, each XCD touches one 2.56 MB wph slice ->
// L2-resident gather.  Because mseg AND group_to_drug are sorted, a drug's
// members are ONE contiguous range [gstart[dstart[d]], gstart[dstart[d+1]]).
// drug_mean = (1/cnt) * sum_t cw[t].inv * wph_c[cw[t].row]  -- flat loop,
// no per-group reductions/stores.  Wave = 4 lane-quarters, each quarter
// handles one member's 128B chunk row (16 lanes x 8B).
// ---------------------------------------------------------------------------
__global__ __launch_bounds__(64) void drug_pool_kernel(
    const unsigned short* __restrict__ wph, const uint2* __restrict__ cw,
    const int* __restrict__ gstart, const int* __restrict__ dstart,
    int ND, int np, unsigned short* __restrict__ dmean) {
  int lane = threadIdx.x;
  int B = blockIdx.x;
  int xcd = B & 7;
  int chunk = xcd >> 1;
  int d0 = ((B >> 3) * 2 + (xcd & 1)) * 2;
  if (d0 >= ND) return;
  const unsigned short* slice = wph + (size_t)chunk * np * 64;
  int quarter = lane >> 4, qlane = lane & 15;
  for (int di = 0; di < 2; ++di) {
    int d = d0 + di;
    if (d >= ND) break;
    int gb = dstart[d], ge = dstart[d + 1];
    int mbeg = gstart[gb], mend = gstart[ge];
    // count non-empty groups of this drug (avg 4 groups -> 1 ballot)
    int cnt = 0;
    for (int base = gb; base < ge; base += 64) {
      int gg = base + lane;
      bool ne = (gg < ge) && (gstart[gg + 1] > gstart[gg]);
      cnt += (int)__popcll(__ballot(ne));
    }
    float4 acc = make_float4(0.f, 0.f, 0.f, 0.f);
    for (int c = mbeg; c < mend; c += 64) {
      int cn = mend - c; if (cn > 64) cn = 64;
#pragma unroll 4
      for (int t = 0; t < cn; t += 4) {
        int src = t + quarter;               // this quarter's member
        if (src < cn) {
          uint2 cwv = cw[c + src];           // 16 lanes same addr: broadcast
          float cf = __uint_as_float(cwv.y);
          uint2 v = *(const uint2*)(slice + ((size_t)cwv.x << 6) + (qlane << 2));
          acc.x += cf * bflo(v.x); acc.y += cf * bfhi(v.x);
          acc.z += cf * bflo(v.y); acc.w += cf * bfhi(v.y);
        }
      }
    }
    // sum partial dims across the 4 quarters (same dims, disjoint members)
    acc.x += __shfl_xor(acc.x, 16, 64); acc.x += __shfl_xor(acc.x, 32, 64);
    acc.y += __shfl_xor(acc.y, 16, 64); acc.y += __shfl_xor(acc.y, 32, 64);
    acc.z += __shfl_xor(acc.z, 16, 64); acc.z += __shfl_xor(acc.z, 32, 64);
    acc.w += __shfl_xor(acc.w, 16, 64); acc.w += __shfl_xor(acc.w, 32, 64);
    float inv = 1.f / fmaxf((float)cnt, 1.f);
    if (quarter == 0) {
      ushort4 st;
      st.x = f2bf(acc.x * inv); st.y = f2bf(acc.y * inv);
      st.z = f2bf(acc.z * inv); st.w = f2bf(acc.w * inv);
      *(ushort4*)(dmean + (size_t)d * HD + (chunk << 6) + (qlane << 2)) = st;
    }
  }
}

// ---------------------------------------------------------------------------
// Kernel 4 (pure GEMM + bias + relu).  Block = 512 threads (8 waves) owns
// 16 drug rows; wave w covers cols [w*32, w*32+32) via mfma_f32_16x16x32_bf16.
// A read straight from global dmean (8KB/block, L1/L2-hot).  C/D layout:
// col=lane&15, row=(lane>>4)*4+j  [verified rounds 4-5 of prior session].
// ---------------------------------------------------------------------------
#define GM 16
__global__ __launch_bounds__(512) void gemm_kernel(
    const unsigned short* __restrict__ A, const unsigned short* __restrict__ Wbf,
    const float* __restrict__ bias, float* __restrict__ out) {
  int wave = threadIdx.x >> 6, lane = threadIdx.x & 63;
  int m0 = blockIdx.x * GM;
  int n0 = wave * 32;
  int arow = lane & 15;
  int apack = lane >> 4;  // 16B k-offset selector
  f32x4 acc[2] = {};
#pragma unroll
  for (int k0 = 0; k0 < HD; k0 += 32) {
    int k = k0 + apack * 8;
    bf16x8 af = *(const bf16x8*)(A + (size_t)(m0 + arow) * HD + k);
#pragma unroll
    for (int t = 0; t < 2; ++t) {
      int col = n0 + t * 16 + arow;
      bf16x8 bfr = *(const bf16x8*)(Wbf + (size_t)col * HD + k);
      acc[t] = __builtin_amdgcn_mfma_f32_16x16x32_bf16(af, bfr, acc[t], 0, 0, 0);
    }
  }
  int rbase = m0 + (lane >> 4) * 4;
#pragma unroll
  for (int t = 0; t < 2; ++t) {
    int col = n0 + t * 16 + (lane & 15);
    float bv = bias[col];
#pragma unroll
    for (int j = 0; j < 4; ++j) {
      out[(size_t)(rbase + j) * HD + col] = fmaxf(acc[t][j] + bv, 0.f);
    }
  }
}

// ---------------------------------------------------------------------------
extern "C" void kernel_launch(void* const* d_in, const int* in_sizes, int n_in,
                              void* d_out, int out_size, void* d_ws, size_t ws_size,
                              hipStream_t stream) {
  const float* protein_h = (const float*)d_in[0];
  const int*   midx      = (const int*)d_in[1];
  const int*   mseg      = (const int*)d_in[2];
  const int*   g2d       = (const int*)d_in[3];
  const float* attn_w    = (const float*)d_in[4];
  const float* proj_W    = (const float*)d_in[5];
  const float* proj_b    = (const float*)d_in[6];
  float* out = (float*)d_out;

  const int NPROT = in_sizes[0] / HD;  // 20000
  const int T  = in_sizes[1];          // 262144
  const int G  = in_sizes[3];          // 16384
  const int NW = in_sizes[5];          // 65536
  const int ND = out_size / HD;        // 4096

  // ws: gstart[G+1] | dstart[ND+1] | etbl[NPROT] | Wbf[NW bf16] |
  //     wph[4*NPROT*64 bf16, chunk-major] | cw[T uint2] | dmean[ND*256 bf16]
  char* ws = (char*)d_ws;
  int* gstart = (int*)ws;
  int* dstart = gstart + (G + 1);
  size_t off = (((size_t)(G + 1) + (size_t)(ND + 1)) * sizeof(int) + 255) & ~(size_t)255;
  float* etbl = (float*)(ws + off);
  off += (((size_t)NPROT * sizeof(float)) + 255) & ~(size_t)255;
  unsigned short* Wbf = (unsigned short*)(ws + off);
  off += (((size_t)NW * sizeof(unsigned short)) + 255) & ~(size_t)255;
  unsigned short* wph = (unsigned short*)(ws + off);
  off += (((size_t)NPROT * HD * sizeof(unsigned short)) + 255) & ~(size_t)255;
  uint2* cw = (uint2*)(ws + off);
  off += (((size_t)T * sizeof(uint2)) + 255) & ~(size_t)255;
  unsigned short* dmean = (unsigned short*)(ws + off);

  int nmax = (T > G ? T : G) + 1;
  int nbb = (nmax + 255) / 256;                 // bounds blocks
  int npb = (NPROT + 3) / 4;                    // protein blocks
  prep_kernel<<<nbb + npb, 256, 0, stream>>>(
      mseg, T, G, gstart, g2d, ND, dstart, proj_W, NW, Wbf,
      protein_h, attn_w, NPROT, etbl, wph, nbb);
  coef_kernel<<<(G + 15) / 16, 256, 0, stream>>>(midx, etbl, gstart, G, cw);
  drug_pool_kernel<<<8 * ((ND + 3) / 4), 64, 0, stream>>>(
      wph, cw, gstart, dstart, ND, NPROT, dmean);
  gemm_kernel<<<ND / GM, 512, 0, stream>>>(dmean, Wbf, proj_b, out);
}

// Round 2
// 55.547 us; speedup vs baseline: 1.0883x; 1.0883x over previous
//
#include <hip/hip_runtime.h>
#include <math.h>

#define HD 256  // hidden dim D

typedef unsigned int uint32;
typedef __attribute__((ext_vector_type(8))) short bf16x8;   // MFMA A/B frag (4 VGPR)
typedef __attribute__((ext_vector_type(4))) float f32x4;    // MFMA C/D frag

// round-to-nearest-even f32 -> bf16 (finite inputs)
__device__ inline unsigned short f2bf(float f) {
  uint32 u = __float_as_uint(f);
  return (unsigned short)((u + 0x7fffu + ((u >> 16) & 1u)) >> 16);
}
__device__ inline float bflo(uint32 v) { return __uint_as_float(v << 16); }
__device__ inline float bfhi(uint32 v) { return __uint_as_float(v & 0xffff0000u); }

// ---------------------------------------------------------------------------
// Kernel 1 (prep): blocks [0, nbb): segment bounds for both sorted arrays +
// f32->bf16 convert of proj_W.  Blocks [nbb, ...): per-protein weight
// e[p] = exp(ph[p].attn_w)  (logits ~N(0,1) -> unshifted exp safe; group
// softmax is shift-invariant) and the premultiplied bf16 table stored
// CHUNK-MAJOR:  wph[chunk][p][64] , chunk = dim/64.  Each 64-dim slice is
// 20000*128B = 2.56 MB -> fits a 4 MiB per-XCD L2 (the key to kernel 2).
// ---------------------------------------------------------------------------
__global__ __launch_bounds__(256) void prep_kernel(
    const int* __restrict__ mseg, int T, int G, int* __restrict__ gstart,
    const int* __restrict__ g2d, int ND, int* __restrict__ dstart,
    const float* __restrict__ W, int NW, unsigned short* __restrict__ Wbf,
    const float* __restrict__ protein_h, const float* __restrict__ attn_w,
    int np, float* __restrict__ etbl, unsigned short* __restrict__ wph,
    int nbb) {
  int b = blockIdx.x;
  if (b < nbb) {
    int t = b * 256 + threadIdx.x;
    if (t <= T) {
      int cur  = (t < T) ? mseg[t] : G;
      int prev = (t == 0) ? -1 : mseg[t - 1];
      for (int g = prev + 1; g <= cur; ++g) gstart[g] = t;
    }
    if (t <= G) {
      int cur  = (t < G) ? g2d[t] : ND;
      int prev = (t == 0) ? -1 : g2d[t - 1];
      for (int d = prev + 1; d <= cur; ++d) dstart[d] = t;
    }
    if (t < NW) Wbf[t] = f2bf(W[t]);
    return;
  }
  int wave = threadIdx.x >> 6, lane = threadIdx.x & 63;
  int p = (b - nbb) * 4 + wave;
  if (p >= np) return;
  float4 w = ((const float4*)attn_w)[lane];
  float4 v = ((const float4*)(protein_h + (size_t)p * HD))[lane];
  float s = v.x * w.x + v.y * w.y + v.z * w.z + v.w * w.w;
#pragma unroll
  for (int o = 32; o > 0; o >>= 1) s += __shfl_xor(s, o, 64);
  float e = __expf(s);
  if (lane == 0) etbl[p] = e;
  ushort4 st;
  st.x = f2bf(e * v.x); st.y = f2bf(e * v.y);
  st.z = f2bf(e * v.z); st.w = f2bf(e * v.w);
  // lane covers dims lane*4..lane*4+3 -> chunk = lane>>4, within = (lane&15)*4
  *(ushort4*)(wph + ((size_t)(lane >> 4) * np + p) * 64 + (lane & 15) * 4) = st;
}

// ---------------------------------------------------------------------------
// Kernel 2 (fused group-softmax pool + drug-mean, chunked XCD-pinned):
// one wave per block, ONE drug, ONE 64-dim chunk.  chunk = (blockIdx%8)>>1:
// blocks round-robin across XCDs, each XCD touches one 2.56 MB wph slice ->
// L2-resident gather.  Since mseg AND group_to_drug are sorted, drug d's
// groups are dstart[d]..dstart[d+1] and each group's members contiguous.
// Per group: coalesced midx load, etbl gather for denom (ONE memory
// indirection; row ids broadcast by register shfl -- the round-1 cw global
// load was a second dependent L2 hop and regressed 5us), raw sums in
// quarter-partials, then 6-shfl denom reduce + scale by 1/denom.  Quarter
// reduction deferred to once per drug; drug mean over non-empty groups.
// ---------------------------------------------------------------------------
__global__ __launch_bounds__(64) void drug_pool_kernel(
    const unsigned short* __restrict__ wph, const int* __restrict__ midx,
    const float* __restrict__ etbl, const int* __restrict__ gstart,
    const int* __restrict__ dstart, int ND, int np,
    unsigned short* __restrict__ dmean) {
  int lane = threadIdx.x;
  int B = blockIdx.x;
  int xcd = B & 7;
  int chunk = xcd >> 1;
  int d = (B >> 3) * 2 + (xcd & 1);
  if (d >= ND) return;
  const unsigned short* slice = wph + (size_t)chunk * np * 64;
  int quarter = lane >> 4, qlane = lane & 15;
  int gb = dstart[d], ge = dstart[d + 1];
  float4 acc = make_float4(0.f, 0.f, 0.f, 0.f);
  float cnt = 0.f;
  int mb = gstart[gb];
  for (int g = gb; g < ge; ++g) {
    int me = gstart[g + 1];
    if (me > mb) {
      float4 gacc = make_float4(0.f, 0.f, 0.f, 0.f);
      float den = 0.f;
      for (int c = mb; c < me; c += 64) {
        int cn = me - c; if (cn > 64) cn = 64;
        int myrow = midx[c + (lane < cn ? lane : 0)];
        if (lane < cn) den += etbl[myrow];
#pragma unroll 4
        for (int t = 0; t < cn; t += 4) {
          int src = t + quarter;               // this quarter's member
          int row = __shfl(myrow, src, 64);    // per-lane src (bpermute)
          if (src < cn) {
            uint2 v = *(const uint2*)(slice + ((size_t)row << 6) + (qlane << 2));
            gacc.x += bflo(v.x); gacc.y += bfhi(v.x);
            gacc.z += bflo(v.y); gacc.w += bfhi(v.y);
          }
        }
      }
#pragma unroll
      for (int o = 32; o > 0; o >>= 1) den += __shfl_xor(den, o, 64);
      float inv = 1.f / den;
      acc.x += gacc.x * inv; acc.y += gacc.y * inv;
      acc.z += gacc.z * inv; acc.w += gacc.w * inv;
      cnt += 1.f;
    }
    mb = me;
  }
  // sum partial dims across the 4 quarters (same dims, disjoint members)
  acc.x += __shfl_xor(acc.x, 16, 64); acc.x += __shfl_xor(acc.x, 32, 64);
  acc.y += __shfl_xor(acc.y, 16, 64); acc.y += __shfl_xor(acc.y, 32, 64);
  acc.z += __shfl_xor(acc.z, 16, 64); acc.z += __shfl_xor(acc.z, 32, 64);
  acc.w += __shfl_xor(acc.w, 16, 64); acc.w += __shfl_xor(acc.w, 32, 64);
  float minv = 1.f / fmaxf(cnt, 1.f);
  if (quarter == 0) {
    ushort4 st;
    st.x = f2bf(acc.x * minv); st.y = f2bf(acc.y * minv);
    st.z = f2bf(acc.z * minv); st.w = f2bf(acc.w * minv);
    *(ushort4*)(dmean + (size_t)d * HD + (chunk << 6) + (qlane << 2)) = st;
  }
}

// ---------------------------------------------------------------------------
// Kernel 3 (pure GEMM + bias + relu).  Block = 512 threads (8 waves) owns
// 16 drug rows; wave w covers cols [w*32, w*32+32) via mfma_f32_16x16x32_bf16.
// A read straight from global dmean (8KB/block, L1/L2-hot).  C/D layout:
// col=lane&15, row=(lane>>4)*4+j  [verified in prior session].
// ---------------------------------------------------------------------------
#define GM 16
__global__ __launch_bounds__(512) void gemm_kernel(
    const unsigned short* __restrict__ A, const unsigned short* __restrict__ Wbf,
    const float* __restrict__ bias, float* __restrict__ out) {
  int wave = threadIdx.x >> 6, lane = threadIdx.x & 63;
  int m0 = blockIdx.x * GM;
  int n0 = wave * 32;
  int arow = lane & 15;
  int apack = lane >> 4;  // 16B k-offset selector
  f32x4 acc[2] = {};
#pragma unroll
  for (int k0 = 0; k0 < HD; k0 += 32) {
    int k = k0 + apack * 8;
    bf16x8 af = *(const bf16x8*)(A + (size_t)(m0 + arow) * HD + k);
#pragma unroll
    for (int t = 0; t < 2; ++t) {
      int col = n0 + t * 16 + arow;
      bf16x8 bfr = *(const bf16x8*)(Wbf + (size_t)col * HD + k);
      acc[t] = __builtin_amdgcn_mfma_f32_16x16x32_bf16(af, bfr, acc[t], 0, 0, 0);
    }
  }
  int rbase = m0 + (lane >> 4) * 4;
#pragma unroll
  for (int t = 0; t < 2; ++t) {
    int col = n0 + t * 16 + (lane & 15);
    float bv = bias[col];
#pragma unroll
    for (int j = 0; j < 4; ++j) {
      out[(size_t)(rbase + j) * HD + col] = fmaxf(acc[t][j] + bv, 0.f);
    }
  }
}

// ---------------------------------------------------------------------------
extern "C" void kernel_launch(void* const* d_in, const int* in_sizes, int n_in,
                              void* d_out, int out_size, void* d_ws, size_t ws_size,
                              hipStream_t stream) {
  const float* protein_h = (const float*)d_in[0];
  const int*   midx      = (const int*)d_in[1];
  const int*   mseg      = (const int*)d_in[2];
  const int*   g2d       = (const int*)d_in[3];
  const float* attn_w    = (const float*)d_in[4];
  const float* proj_W    = (const float*)d_in[5];
  const float* proj_b    = (const float*)d_in[6];
  float* out = (float*)d_out;

  const int NPROT = in_sizes[0] / HD;  // 20000
  const int T  = in_sizes[1];          // 262144
  const int G  = in_sizes[3];          // 16384
  const int NW = in_sizes[5];          // 65536
  const int ND = out_size / HD;        // 4096

  // ws: gstart[G+1] | dstart[ND+1] | etbl[NPROT] | Wbf[NW bf16] |
  //     wph[4*NPROT*64 bf16, chunk-major] | dmean[ND*256 bf16]
  char* ws = (char*)d_ws;
  int* gstart = (int*)ws;
  int* dstart = gstart + (G + 1);
  size_t off = (((size_t)(G + 1) + (size_t)(ND + 1)) * sizeof(int) + 255) & ~(size_t)255;
  float* etbl = (float*)(ws + off);
  off += (((size_t)NPROT * sizeof(float)) + 255) & ~(size_t)255;
  unsigned short* Wbf = (unsigned short*)(ws + off);
  off += (((size_t)NW * sizeof(unsigned short)) + 255) & ~(size_t)255;
  unsigned short* wph = (unsigned short*)(ws + off);
  off += (((size_t)NPROT * HD * sizeof(unsigned short)) + 255) & ~(size_t)255;
  unsigned short* dmean = (unsigned short*)(ws + off);

  int nmax = (T > G ? T : G) + 1;
  int nbb = (nmax + 255) / 256;                 // bounds blocks
  int npb = (NPROT + 3) / 4;                    // protein blocks
  prep_kernel<<<nbb + npb, 256, 0, stream>>>(
      mseg, T, G, gstart, g2d, ND, dstart, proj_W, NW, Wbf,
      protein_h, attn_w, NPROT, etbl, wph, nbb);
  drug_pool_kernel<<<8 * ((ND + 1) / 2), 64, 0, stream>>>(
      wph, midx, etbl, gstart, dstart, ND, NPROT, dmean);
  gemm_kernel<<<ND / GM, 512, 0, stream>>>(dmean, Wbf, proj_b, out);
}